// Round 7
// baseline (1887.779 us; speedup 1.0000x reference)
//
#include <hip/hip_runtime.h>
#include <hip/hip_bf16.h>

#define NN 100000
#define NE 250000
#define DD 300
#define DDB 304       // bf16 h row stride (16B aligned)
#define NL 5
#define MPAD 100096   // 391*256 == 782*128
#define KA1 320       // padded K for GEMM1 (300->320)
#define N1 608        // padded width of m1 (600->608), also K of GEMM2
#define N1T 640       // padded rows of W1T (5 tiles * 128)
#define K2 608
#define N2T 384       // padded rows of W2T (300->384)
#define NBLK 391      // ceil(NN/256)
#define NCMB 19       // 18 (bt*3+bd) combos + self at 18

typedef __attribute__((ext_vector_type(8))) short short8;
typedef __attribute__((ext_vector_type(4))) float f32x4;

#define GLBP(x) ((const __attribute__((address_space(1))) unsigned int*)(x))
#define LDSP(x) ((__attribute__((address_space(3))) unsigned int*)(x))
#define WAITV(N) asm volatile("s_waitcnt vmcnt(" #N ")" ::: "memory")

__device__ __forceinline__ ushort f2bf(float f){
  unsigned u = __float_as_uint(f);
  u += 0x7FFFu + ((u >> 16) & 1u);
  return (ushort)(u >> 16);
}
__device__ __forceinline__ float bf2f(ushort h){
  return __uint_as_float((unsigned)h << 16);
}
__device__ __forceinline__ unsigned pk2(float a, float b){
  return (unsigned)f2bf(a) | ((unsigned)f2bf(b) << 16);
}

// ---------------- weight prep: transpose + f32->bf16, zero-padded ----------
__global__ void prep_weights(const float* __restrict__ W1, const float* __restrict__ W2,
                             ushort* __restrict__ W1T, ushort* __restrict__ W2T){
  int idx = blockIdx.x * 256 + threadIdx.x;
  const int total1 = NL * N1T * KA1;
  const int total2 = NL * N2T * K2;
  if (idx < total1){
    int l = idx / (N1T * KA1);
    int rem = idx % (N1T * KA1);
    int n = rem / KA1, k = rem % KA1;
    float v = (n < 2*DD && k < DD) ? W1[(size_t)l*DD*2*DD + (size_t)k*2*DD + n] : 0.0f;
    W1T[idx] = f2bf(v);
  } else {
    int idx2 = idx - total1;
    if (idx2 < total2){
      int l = idx2 / (N2T * K2);
      int rem = idx2 % (N2T * K2);
      int n = rem / K2, k = rem % K2;
      float v = (n < DD && k < 2*DD) ? W2[(size_t)l*2*DD*DD + (size_t)k*DD + n] : 0.0f;
      W2T[idx2] = f2bf(v);
    }
  }
}

// -------- combo tables: ctab[l][c][d] = E1[l][c/3][d] + E2[l][c%3][d] ------
__global__ void prep_ctab(const float* __restrict__ E1, const float* __restrict__ E2,
                          float* __restrict__ ctab){
  int idx = blockIdx.x * 256 + threadIdx.x;
  if (idx >= NL * NCMB * DDB) return;
  int l = idx / (NCMB * DDB);
  int rem = idx % (NCMB * DDB);
  int c = rem / DDB, d = rem % DDB;
  float v = 0.0f;
  if (d < DD){
    int bt = (c < 18) ? (c / 3) : 4;
    int bd = (c < 18) ? (c % 3) : 0;
    v = E1[(size_t)l*6*DD + bt*DD + d] + E2[(size_t)l*3*DD + bd*DD + d];
  }
  ctab[idx] = v;
}

// ---------------- CSR build ------------------------------------------------
__global__ void csr_count(const int* __restrict__ ei, int* __restrict__ deg){
  int e = blockIdx.x * 256 + threadIdx.x;
  if (e < NE) atomicAdd(&deg[ei[NE + e]], 1);
}

__global__ void scan_blk(const int* __restrict__ deg, int* __restrict__ rs, int* __restrict__ bsum){
  __shared__ int tmp[256];
  int i = blockIdx.x * 256 + threadIdx.x;
  int v = (i < NN) ? deg[i] : 0;
  tmp[threadIdx.x] = v;
  __syncthreads();
  #pragma unroll
  for (int off = 1; off < 256; off <<= 1){
    int t = (threadIdx.x >= off) ? tmp[threadIdx.x - off] : 0;
    __syncthreads();
    tmp[threadIdx.x] += t;
    __syncthreads();
  }
  if (i < NN) rs[i] = tmp[threadIdx.x] - v;   // exclusive
  if (threadIdx.x == 255) bsum[blockIdx.x] = tmp[255];
}

__global__ void scan_top(int* __restrict__ bsum){
  __shared__ int tmp[512];
  int v = (threadIdx.x < NBLK) ? bsum[threadIdx.x] : 0;
  tmp[threadIdx.x] = v;
  __syncthreads();
  #pragma unroll
  for (int off = 1; off < 512; off <<= 1){
    int t = (threadIdx.x >= off) ? tmp[threadIdx.x - off] : 0;
    __syncthreads();
    tmp[threadIdx.x] += t;
    __syncthreads();
  }
  if (threadIdx.x < NBLK) bsum[threadIdx.x] = tmp[threadIdx.x] - v; // exclusive
}

__global__ void scan_add(int* __restrict__ rs, const int* __restrict__ bsum){
  int i = blockIdx.x * 256 + threadIdx.x;
  if (i < NN) rs[i] += bsum[blockIdx.x];
  if (i == 0) rs[NN] = NE;
}

__global__ void csr_fill(const int* __restrict__ ei, const int* __restrict__ ea,
                         const int* __restrict__ rs, int* __restrict__ cursor,
                         int* __restrict__ edges){
  int e = blockIdx.x * 256 + threadIdx.x;
  if (e < NE){
    int dst = ei[NE + e];
    int src = ei[e];
    int c = ea[2*e] * 3 + ea[2*e + 1];
    int p = rs[dst] + atomicAdd(&cursor[dst], 1);
    edges[p] = src | (c << 20);
  }
}

// ---- gather: wave-per-row, grid-stride. 2 tranches: dA=lane*4 (0..255),
// ---- dB=256+lane*4 (lanes 0..15; data valid lanes 0..10). ----
template<int HBF>
__global__ __launch_bounds__(256) void gather_agg(
    const void* __restrict__ hp, const float2* __restrict__ ss,
    const float* __restrict__ ctab_l,
    const int* __restrict__ rs, const int* __restrict__ edges,
    ushort* __restrict__ agg)
{
  int lane = threadIdx.x & 63;
  int wq = __builtin_amdgcn_readfirstlane(threadIdx.x >> 6);
  int wid = blockIdx.x * 4 + wq;
  int nw = gridDim.x * 4;
  int dA = lane * 4;
  int dB = 256 + lane * 4;
  bool laneB  = (lane < 16);
  bool validB = (dB < DD);         // lanes 0..10

  float scA[4], shA[4], scB[4], shB[4];
  if (HBF){
    #pragma unroll
    for (int j = 0; j < 4; ++j){
      float2 s = ss[dA + j]; scA[j] = s.x; shA[j] = s.y;
    }
    if (validB){
      #pragma unroll
      for (int j = 0; j < 4; ++j){
        float2 s = ss[dB + j]; scB[j] = s.x; shB[j] = s.y;
      }
    }
  }

  const float*  hf = (const float*)hp;
  const ushort* hb = (const ushort*)hp;
  const float* ctS = ctab_l + 18*DDB;

  for (int row = wid; row < MPAD; row += nw){
    float a0=0,a1=0,a2=0,a3=0, b0=0,b1=0,b2=0,b3=0;
    if (row < NN){
      if (HBF){
        uint2 hw = *(const uint2*)(hb + (size_t)row*DDB + dA);
        a0 = fmaxf(bf2f((ushort)hw.x)*scA[0]+shA[0],0.f)      + ctS[dA+0];
        a1 = fmaxf(bf2f((ushort)(hw.x>>16))*scA[1]+shA[1],0.f)+ ctS[dA+1];
        a2 = fmaxf(bf2f((ushort)hw.y)*scA[2]+shA[2],0.f)      + ctS[dA+2];
        a3 = fmaxf(bf2f((ushort)(hw.y>>16))*scA[3]+shA[3],0.f)+ ctS[dA+3];
        if (validB){
          uint2 hv = *(const uint2*)(hb + (size_t)row*DDB + dB);
          b0 = fmaxf(bf2f((ushort)hv.x)*scB[0]+shB[0],0.f)      + ctS[dB+0];
          b1 = fmaxf(bf2f((ushort)(hv.x>>16))*scB[1]+shB[1],0.f)+ ctS[dB+1];
          b2 = fmaxf(bf2f((ushort)hv.y)*scB[2]+shB[2],0.f)      + ctS[dB+2];
          b3 = fmaxf(bf2f((ushort)(hv.y>>16))*scB[3]+shB[3],0.f)+ ctS[dB+3];
        }
      } else {
        float4 hv = *(const float4*)(hf + (size_t)row*DD + dA);
        a0 = hv.x + ctS[dA+0]; a1 = hv.y + ctS[dA+1];
        a2 = hv.z + ctS[dA+2]; a3 = hv.w + ctS[dA+3];
        if (validB){
          float4 hv2 = *(const float4*)(hf + (size_t)row*DD + dB);
          b0 = hv2.x + ctS[dB+0]; b1 = hv2.y + ctS[dB+1];
          b2 = hv2.z + ctS[dB+2]; b3 = hv2.w + ctS[dB+3];
        }
      }
      int p = rs[row], pe = rs[row + 1];
      for (; p < pe; ++p){
        int ew = edges[p];
        int src = ew & 0xFFFFF;
        const float* ct = ctab_l + (ew >> 20)*DDB;
        if (HBF){
          uint2 hw = *(const uint2*)(hb + (size_t)src*DDB + dA);
          a0 += fmaxf(bf2f((ushort)hw.x)*scA[0]+shA[0],0.f)      + ct[dA+0];
          a1 += fmaxf(bf2f((ushort)(hw.x>>16))*scA[1]+shA[1],0.f)+ ct[dA+1];
          a2 += fmaxf(bf2f((ushort)hw.y)*scA[2]+shA[2],0.f)      + ct[dA+2];
          a3 += fmaxf(bf2f((ushort)(hw.y>>16))*scA[3]+shA[3],0.f)+ ct[dA+3];
          if (validB){
            uint2 hv = *(const uint2*)(hb + (size_t)src*DDB + dB);
            b0 += fmaxf(bf2f((ushort)hv.x)*scB[0]+shB[0],0.f)      + ct[dB+0];
            b1 += fmaxf(bf2f((ushort)(hv.x>>16))*scB[1]+shB[1],0.f)+ ct[dB+1];
            b2 += fmaxf(bf2f((ushort)hv.y)*scB[2]+shB[2],0.f)      + ct[dB+2];
            b3 += fmaxf(bf2f((ushort)(hv.y>>16))*scB[3]+shB[3],0.f)+ ct[dB+3];
          }
        } else {
          float4 hv = *(const float4*)(hf + (size_t)src*DD + dA);
          a0 += hv.x + ct[dA+0]; a1 += hv.y + ct[dA+1];
          a2 += hv.z + ct[dA+2]; a3 += hv.w + ct[dA+3];
          if (validB){
            float4 hv2 = *(const float4*)(hf + (size_t)src*DD + dB);
            b0 += hv2.x + ct[dB+0]; b1 += hv2.y + ct[dB+1];
            b2 += hv2.z + ct[dB+2]; b3 += hv2.w + ct[dB+3];
          }
        }
      }
    }
    ushort* ag = agg + (size_t)row*KA1;
    uint2 oA; oA.x = pk2(a0, a1); oA.y = pk2(a2, a3);
    *(uint2*)(ag + dA) = oA;
    if (laneB){
      uint2 oB;
      if (validB){ oB.x = pk2(b0, b1); oB.y = pk2(b2, b3); }
      else       { oB.x = 0; oB.y = 0; }
      *(uint2*)(ag + dB) = oB;
    }
  }
}

// ---- bf16 MFMA GEMM, 128x128 tile, BK=32, 5-buf depth-4 counted vmcnt -----
// 256 threads, 4 waves (2m x 2n), wave tile 64x64 (4x4 frags).
// k-slot swizzle (rule #21) + bijective chunked XCD swizzle (m204).
// Depth-4 prefetch: tile kt+4 issued at iter kt; vmcnt(12) = tile kt+1
// landed with 3 tiles still in flight (~4 iterations of latency coverage).
template<int OUT_BF16, int RELU, int STATS>
__global__ __launch_bounds__(256) void gemm_lds(
    const ushort* __restrict__ A, int lda,
    const ushort* __restrict__ B, int ldb,
    void* __restrict__ Cp, int ldc,
    int kTiles, const float* __restrict__ bias, int biasN,
    int Mvalid, int Nvalid, int nColTiles, float* __restrict__ statf)
{
  __shared__ ushort As[5][4096];   // 128 rows x 32, x5 bufs
  __shared__ ushort Bs[5][4096];
  int tid = threadIdx.x;
  int lane = tid & 63, w = tid >> 6;
  int wm = (w >> 1) * 64, wn = (w & 1) * 64;

  // bijective chunked XCD swizzle
  int nwg = gridDim.x;
  int q = nwg >> 3, r = nwg & 7;
  int xcd = blockIdx.x & 7, idx = blockIdx.x >> 3;
  int bid = (xcd < r ? xcd * (q + 1) : r * (q + 1) + (xcd - r) * q) + idx;
  int m0 = (bid / nColTiles) * 128;
  int n0 = (bid % nColTiles) * 128;

  int r0 = tid >> 2;                            // 0..63: row within 64-row half
  int kc = ((tid & 3) ^ ((tid >> 3) & 3)) * 8;  // inverse-swizzled k-chunk
  const ushort* Ap = A + (size_t)(m0 + r0)*lda + kc;
  const ushort* Bp = B + (size_t)(n0 + r0)*ldb + kc;

  f32x4 acc[4][4] = {};

#define STAGE(buf, kt) do { \
    int _ko = (kt) * 32; \
    __builtin_amdgcn_global_load_lds(GLBP(Ap + _ko),                  LDSP(&As[buf][w*512]),        16, 0, 0); \
    __builtin_amdgcn_global_load_lds(GLBP(Ap + _ko + (size_t)64*lda), LDSP(&As[buf][w*512 + 2048]), 16, 0, 0); \
    __builtin_amdgcn_global_load_lds(GLBP(Bp + _ko),                  LDSP(&Bs[buf][w*512]),        16, 0, 0); \
    __builtin_amdgcn_global_load_lds(GLBP(Bp + _ko + (size_t)64*ldb), LDSP(&Bs[buf][w*512 + 2048]), 16, 0, 0); \
  } while (0)

  STAGE(0, 0); STAGE(1, 1); STAGE(2, 2); STAGE(3, 3);
  WAITV(12);                        // tile 0 landed; 1..3 in flight
  __builtin_amdgcn_s_barrier();

  int fr = lane & 15;
  int ko8 = (((lane >> 4) ^ ((fr >> 1) & 3))) * 8;   // swizzled read k-offset
  int cur = 0;
  for (int kt = 0; kt < kTiles; ++kt){
    int sb = cur + 4; if (sb >= 5) sb -= 5;
    if (kt + 4 < kTiles) STAGE(sb, kt + 4);
    short8 af[4], bfv[4];
    #pragma unroll
    for (int i = 0; i < 4; ++i)
      af[i] = *(const short8*)&As[cur][(wm + i*16 + fr)*32 + ko8];
    #pragma unroll
    for (int j = 0; j < 4; ++j)
      bfv[j] = *(const short8*)&Bs[cur][(wn + j*16 + fr)*32 + ko8];
    #pragma unroll
    for (int i = 0; i < 4; ++i)
      #pragma unroll
      for (int j = 0; j < 4; ++j)
        acc[i][j] = __builtin_amdgcn_mfma_f32_16x16x32_bf16(af[i], bfv[j], acc[i][j], 0, 0, 0);
    if (kt + 1 < kTiles){
      int rem = kTiles - kt;        // iterations remaining incl. current
      if      (rem >= 5) WAITV(12); // tile kt+1 landed; kt+2..kt+4 in flight
      else if (rem == 4) WAITV(8);
      else if (rem == 3) WAITV(4);
      else               WAITV(0);
      __builtin_amdgcn_s_barrier();
    }
    cur = cur + 1; if (cur >= 5) cur = 0;
  }
#undef STAGE

  int cc = lane & 15, cr = (lane >> 4) * 4;
  float ps[4], pq[4];
  if (STATS){
    #pragma unroll
    for (int j = 0; j < 4; ++j){ ps[j] = 0.0f; pq[j] = 0.0f; }
  }
  #pragma unroll
  for (int i = 0; i < 4; ++i){
    #pragma unroll
    for (int j = 0; j < 4; ++j){
      int col = n0 + wn + j*16 + cc;
      if (col >= Nvalid) continue;
      float bv = (col < biasN) ? bias[col] : 0.0f;
      #pragma unroll
      for (int r2 = 0; r2 < 4; ++r2){
        int row = m0 + wm + i*16 + cr + r2;
        if (row < Mvalid){
          float v = acc[i][j][r2] + bv;
          if (RELU) v = fmaxf(v, 0.0f);
          if (OUT_BF16) ((ushort*)Cp)[(size_t)row*ldc + col] = f2bf(v);
          else          ((float*) Cp)[(size_t)row*ldc + col] = v;
          if (STATS){ ps[j] += v; pq[j] += v * v; }
        }
      }
    }
  }
  if (STATS){
    #pragma unroll
    for (int j = 0; j < 4; ++j){
      float s = ps[j], qv = pq[j];
      s += __shfl_xor(s, 16); qv += __shfl_xor(qv, 16);
      s += __shfl_xor(s, 32); qv += __shfl_xor(qv, 32);
      int col = n0 + wn + j*16 + cc;
      if ((lane >> 4) == 0 && col < Nvalid){
        unsafeAtomicAdd(&statf[col], s);
        unsafeAtomicAdd(&statf[N2T + col], qv);
      }
    }
  }
}

// ---------------- per-column scale/shift from stats ------------------------
__global__ void make_norm(const float* __restrict__ statf, const float* __restrict__ gamma,
                          const float* __restrict__ beta, float2* __restrict__ ss){
  int d = threadIdx.x;
  if (d >= DD) return;
  double mu = (double)statf[d] / (double)NN;
  double var = (double)statf[N2T + d] / (double)NN - mu * mu;
  float inv = rsqrtf((float)var + 1e-5f);
  float sc = inv * gamma[d];
  ss[d] = make_float2(sc, beta[d] - (float)mu * sc);
}

// ---------------- final norm (no relu) -> d_out ----------------------------
__global__ void apply_norm(const float* __restrict__ m2, const float2* __restrict__ ss,
                           float* __restrict__ out){
  int row = blockIdx.x;
  int d = threadIdx.x;
  if (d >= DD) return;
  float2 s = ss[d];
  out[(size_t)row*DD + d] = m2[(size_t)row*DD + d] * s.x + s.y;
}

extern "C" void kernel_launch(void* const* d_in, const int* in_sizes, int n_in,
                              void* d_out, int out_size, void* d_ws, size_t ws_size,
                              hipStream_t stream) {
  const float* x     = (const float*)d_in[0];
  const int*   ei    = (const int*)  d_in[1];
  const int*   ea    = (const int*)  d_in[2];
  const float* W1    = (const float*)d_in[3];
  const float* b1    = (const float*)d_in[4];
  const float* W2    = (const float*)d_in[5];
  const float* b2    = (const float*)d_in[6];
  const float* E1    = (const float*)d_in[7];
  const float* E2    = (const float*)d_in[8];
  const float* gamma = (const float*)d_in[9];
  const float* beta  = (const float*)d_in[10];

  char* p = (char*)d_ws;
  float*  m2buf = (float*) p; p += (size_t)NN * DD * 4;          // 120,000,000
  ushort* m2bf  = (ushort*)p; p += (size_t)NN * DDB * 2;         //  60,800,000
  ushort* agg   = (ushort*)p; p += (size_t)MPAD * KA1 * 2;       //  64,061,440
  ushort* m1    = (ushort*)p; p += (size_t)MPAD * N1 * 2;        // 121,716,736
  ushort* W1T   = (ushort*)p; p += (size_t)NL * N1T * KA1 * 2;   //   2,048,000
  ushort* W2T   = (ushort*)p; p += (size_t)NL * N2T * K2 * 2;    //   2,334,720
  float*  ctab  = (float*) p; p += (size_t)NL * NCMB * DDB * 4;  //     115,520
  int*    deg   = (int*)   p; p += (size_t)NN * 4;               //     400,000
  int*    rs    = (int*)   p; p += (size_t)(NN + 16) * 4;        //     400,064
  int*    bsum  = (int*)   p; p += (size_t)512 * 4;              //       2,048
  int*    cursor= (int*)   p; p += (size_t)NN * 4;               //     400,000
  int*    edges = (int*)   p; p += (size_t)NE * 4;               //   1,000,000
  float*  statf = (float*) p; p += (size_t)2 * N2T * 4;          //       3,072
  float2* ss    = (float2*)p;                                    //       2,400

  // once-per-launch prep
  {
    int total = NL*N1T*KA1 + NL*N2T*K2;
    prep_weights<<<(total + 255)/256, 256, 0, stream>>>(W1, W2, W1T, W2T);
    int tc = NL * NCMB * DDB;
    prep_ctab<<<(tc + 255)/256, 256, 0, stream>>>(E1, E2, ctab);
  }
  hipMemsetAsync(deg, 0, (size_t)NN*4, stream);
  hipMemsetAsync(cursor, 0, (size_t)NN*4, stream);
  csr_count<<<(NE + 255)/256, 256, 0, stream>>>(ei, deg);
  scan_blk<<<NBLK, 256, 0, stream>>>(deg, rs, bsum);
  scan_top<<<1, 512, 0, stream>>>(bsum);
  scan_add<<<NBLK, 256, 0, stream>>>(rs, bsum);
  csr_fill<<<(NE + 255)/256, 256, 0, stream>>>(ei, ea, rs, cursor, edges);

  for (int l = 0; l < NL; ++l){
    const float* ctab_l = ctab + (size_t)l * NCMB * DDB;

    if (l == 0)
      gather_agg<0><<<1024, 256, 0, stream>>>(x, nullptr, ctab_l, rs, edges, agg);
    else
      gather_agg<1><<<1024, 256, 0, stream>>>(m2bf, ss, ctab_l, rs, edges, agg);

    // m1 = relu(agg @ W1 + b1)  -> bf16 [MPAD][608]
    gemm_lds<1,1,0><<<(MPAD/128) * (N1T/128), 256, 0, stream>>>(
        agg, KA1, W1T + (size_t)l*N1T*KA1, KA1, m1, N1, KA1/32,
        b1 + (size_t)l*2*DD, 2*DD, MPAD, N1, N1T/128, nullptr);

    hipMemsetAsync(statf, 0, (size_t)2*N2T*4, stream);

    // m2 = m1 @ W2 + b2 (+ fused per-column sum/sumsq)
    if (l < NL - 1)
      gemm_lds<1,0,1><<<(MPAD/128) * (N2T/128), 256, 0, stream>>>(
          m1, N1, W2T + (size_t)l*N2T*K2, K2, m2bf, DDB, K2/32,
          b2 + (size_t)l*DD, DD, NN, DD, N2T/128, statf);
    else
      gemm_lds<0,0,1><<<(MPAD/128) * (N2T/128), 256, 0, stream>>>(
          m1, N1, W2T + (size_t)l*N2T*K2, K2, m2buf, DD, K2/32,
          b2 + (size_t)l*DD, DD, NN, DD, N2T/128, statf);

    make_norm<<<1, 320, 0, stream>>>(statf, gamma + (size_t)l*DD, beta + (size_t)l*DD, ss);
  }
  apply_norm<<<NN, 320, 0, stream>>>(m2buf, ss, (float*)d_out);
}

// Round 8
// 1753.122 us; speedup vs baseline: 1.0768x; 1.0768x over previous
//
#include <hip/hip_runtime.h>
#include <hip/hip_bf16.h>

#define NN 100000
#define NE 250000
#define DD 300
#define DDB 304       // bf16 h row stride (16B aligned)
#define NL 5
#define MPAD 100096   // 391*256 == 782*128
#define KA1 320       // padded K for GEMM1 (300->320)
#define N1 608        // padded width of m1 (600->608), also K of GEMM2
#define N1T 640       // padded rows of W1T (5 tiles * 128)
#define K2 608
#define N2T 384       // padded rows of W2T (300->384)
#define NBLK 391      // ceil(NN/256)
#define NCMB 19       // 18 (bt*3+bd) combos + self at 18

typedef __attribute__((ext_vector_type(8))) short short8;
typedef __attribute__((ext_vector_type(4))) float f32x4;

#define GLBP(x) ((const __attribute__((address_space(1))) unsigned int*)(x))
#define LDSP(x) ((__attribute__((address_space(3))) unsigned int*)(x))
#define WAITV(N) asm volatile("s_waitcnt vmcnt(" #N ")" ::: "memory")

__device__ __forceinline__ ushort f2bf(float f){
  unsigned u = __float_as_uint(f);
  u += 0x7FFFu + ((u >> 16) & 1u);
  return (ushort)(u >> 16);
}
__device__ __forceinline__ float bf2f(ushort h){
  return __uint_as_float((unsigned)h << 16);
}
__device__ __forceinline__ unsigned pk2(float a, float b){
  return (unsigned)f2bf(a) | ((unsigned)f2bf(b) << 16);
}

// ---------------- weight prep: transpose + f32->bf16, zero-padded ----------
__global__ void prep_weights(const float* __restrict__ W1, const float* __restrict__ W2,
                             ushort* __restrict__ W1T, ushort* __restrict__ W2T){
  int idx = blockIdx.x * 256 + threadIdx.x;
  const int total1 = NL * N1T * KA1;
  const int total2 = NL * N2T * K2;
  if (idx < total1){
    int l = idx / (N1T * KA1);
    int rem = idx % (N1T * KA1);
    int n = rem / KA1, k = rem % KA1;
    float v = (n < 2*DD && k < DD) ? W1[(size_t)l*DD*2*DD + (size_t)k*2*DD + n] : 0.0f;
    W1T[idx] = f2bf(v);
  } else {
    int idx2 = idx - total1;
    if (idx2 < total2){
      int l = idx2 / (N2T * K2);
      int rem = idx2 % (N2T * K2);
      int n = rem / K2, k = rem % K2;
      float v = (n < DD && k < 2*DD) ? W2[(size_t)l*2*DD*DD + (size_t)k*DD + n] : 0.0f;
      W2T[idx2] = f2bf(v);
    }
  }
}

// -------- combo tables: ctab[l][c][d] = E1[l][c/3][d] + E2[l][c%3][d] ------
__global__ void prep_ctab(const float* __restrict__ E1, const float* __restrict__ E2,
                          float* __restrict__ ctab){
  int idx = blockIdx.x * 256 + threadIdx.x;
  if (idx >= NL * NCMB * DDB) return;
  int l = idx / (NCMB * DDB);
  int rem = idx % (NCMB * DDB);
  int c = rem / DDB, d = rem % DDB;
  float v = 0.0f;
  if (d < DD){
    int bt = (c < 18) ? (c / 3) : 4;
    int bd = (c < 18) ? (c % 3) : 0;
    v = E1[(size_t)l*6*DD + bt*DD + d] + E2[(size_t)l*3*DD + bd*DD + d];
  }
  ctab[idx] = v;
}

// ---------------- CSR build ------------------------------------------------
__global__ void csr_count(const int* __restrict__ ei, int* __restrict__ deg){
  int e = blockIdx.x * 256 + threadIdx.x;
  if (e < NE) atomicAdd(&deg[ei[NE + e]], 1);
}

__global__ void scan_blk(const int* __restrict__ deg, int* __restrict__ rs, int* __restrict__ bsum){
  __shared__ int tmp[256];
  int i = blockIdx.x * 256 + threadIdx.x;
  int v = (i < NN) ? deg[i] : 0;
  tmp[threadIdx.x] = v;
  __syncthreads();
  #pragma unroll
  for (int off = 1; off < 256; off <<= 1){
    int t = (threadIdx.x >= off) ? tmp[threadIdx.x - off] : 0;
    __syncthreads();
    tmp[threadIdx.x] += t;
    __syncthreads();
  }
  if (i < NN) rs[i] = tmp[threadIdx.x] - v;   // exclusive
  if (threadIdx.x == 255) bsum[blockIdx.x] = tmp[255];
}

__global__ void scan_top(int* __restrict__ bsum){
  __shared__ int tmp[512];
  int v = (threadIdx.x < NBLK) ? bsum[threadIdx.x] : 0;
  tmp[threadIdx.x] = v;
  __syncthreads();
  #pragma unroll
  for (int off = 1; off < 512; off <<= 1){
    int t = (threadIdx.x >= off) ? tmp[threadIdx.x - off] : 0;
    __syncthreads();
    tmp[threadIdx.x] += t;
    __syncthreads();
  }
  if (threadIdx.x < NBLK) bsum[threadIdx.x] = tmp[threadIdx.x] - v; // exclusive
}

__global__ void scan_add(int* __restrict__ rs, const int* __restrict__ bsum){
  int i = blockIdx.x * 256 + threadIdx.x;
  if (i < NN) rs[i] += bsum[blockIdx.x];
  if (i == 0) rs[NN] = NE;
}

__global__ void csr_fill(const int* __restrict__ ei, const int* __restrict__ ea,
                         const int* __restrict__ rs, int* __restrict__ cursor,
                         int* __restrict__ edges){
  int e = blockIdx.x * 256 + threadIdx.x;
  if (e < NE){
    int dst = ei[NE + e];
    int src = ei[e];
    int c = ea[2*e] * 3 + ea[2*e + 1];
    int p = rs[dst] + atomicAdd(&cursor[dst], 1);
    edges[p] = src | (c << 20);
  }
}

// ---- gather: wave-per-row, grid-stride. 2 tranches: dA=lane*4 (0..255),
// ---- dB=256+lane*4 (lanes 0..15; data valid lanes 0..10). ----
template<int HBF>
__global__ __launch_bounds__(256) void gather_agg(
    const void* __restrict__ hp, const float2* __restrict__ ss,
    const float* __restrict__ ctab_l,
    const int* __restrict__ rs, const int* __restrict__ edges,
    ushort* __restrict__ agg)
{
  int lane = threadIdx.x & 63;
  int wq = __builtin_amdgcn_readfirstlane(threadIdx.x >> 6);
  int wid = blockIdx.x * 4 + wq;
  int nw = gridDim.x * 4;
  int dA = lane * 4;
  int dB = 256 + lane * 4;
  bool laneB  = (lane < 16);
  bool validB = (dB < DD);         // lanes 0..10

  float scA[4], shA[4], scB[4], shB[4];
  if (HBF){
    #pragma unroll
    for (int j = 0; j < 4; ++j){
      float2 s = ss[dA + j]; scA[j] = s.x; shA[j] = s.y;
    }
    if (validB){
      #pragma unroll
      for (int j = 0; j < 4; ++j){
        float2 s = ss[dB + j]; scB[j] = s.x; shB[j] = s.y;
      }
    }
  }

  const float*  hf = (const float*)hp;
  const ushort* hb = (const ushort*)hp;
  const float* ctS = ctab_l + 18*DDB;

  for (int row = wid; row < MPAD; row += nw){
    float a0=0,a1=0,a2=0,a3=0, b0=0,b1=0,b2=0,b3=0;
    if (row < NN){
      if (HBF){
        uint2 hw = *(const uint2*)(hb + (size_t)row*DDB + dA);
        a0 = fmaxf(bf2f((ushort)hw.x)*scA[0]+shA[0],0.f)      + ctS[dA+0];
        a1 = fmaxf(bf2f((ushort)(hw.x>>16))*scA[1]+shA[1],0.f)+ ctS[dA+1];
        a2 = fmaxf(bf2f((ushort)hw.y)*scA[2]+shA[2],0.f)      + ctS[dA+2];
        a3 = fmaxf(bf2f((ushort)(hw.y>>16))*scA[3]+shA[3],0.f)+ ctS[dA+3];
        if (validB){
          uint2 hv = *(const uint2*)(hb + (size_t)row*DDB + dB);
          b0 = fmaxf(bf2f((ushort)hv.x)*scB[0]+shB[0],0.f)      + ctS[dB+0];
          b1 = fmaxf(bf2f((ushort)(hv.x>>16))*scB[1]+shB[1],0.f)+ ctS[dB+1];
          b2 = fmaxf(bf2f((ushort)hv.y)*scB[2]+shB[2],0.f)      + ctS[dB+2];
          b3 = fmaxf(bf2f((ushort)(hv.y>>16))*scB[3]+shB[3],0.f)+ ctS[dB+3];
        }
      } else {
        float4 hv = *(const float4*)(hf + (size_t)row*DD + dA);
        a0 = hv.x + ctS[dA+0]; a1 = hv.y + ctS[dA+1];
        a2 = hv.z + ctS[dA+2]; a3 = hv.w + ctS[dA+3];
        if (validB){
          float4 hv2 = *(const float4*)(hf + (size_t)row*DD + dB);
          b0 = hv2.x + ctS[dB+0]; b1 = hv2.y + ctS[dB+1];
          b2 = hv2.z + ctS[dB+2]; b3 = hv2.w + ctS[dB+3];
        }
      }
      int p = rs[row], pe = rs[row + 1];
      for (; p < pe; ++p){
        int ew = edges[p];
        int src = ew & 0xFFFFF;
        const float* ct = ctab_l + (ew >> 20)*DDB;
        if (HBF){
          uint2 hw = *(const uint2*)(hb + (size_t)src*DDB + dA);
          a0 += fmaxf(bf2f((ushort)hw.x)*scA[0]+shA[0],0.f)      + ct[dA+0];
          a1 += fmaxf(bf2f((ushort)(hw.x>>16))*scA[1]+shA[1],0.f)+ ct[dA+1];
          a2 += fmaxf(bf2f((ushort)hw.y)*scA[2]+shA[2],0.f)      + ct[dA+2];
          a3 += fmaxf(bf2f((ushort)(hw.y>>16))*scA[3]+shA[3],0.f)+ ct[dA+3];
          if (validB){
            uint2 hv = *(const uint2*)(hb + (size_t)src*DDB + dB);
            b0 += fmaxf(bf2f((ushort)hv.x)*scB[0]+shB[0],0.f)      + ct[dB+0];
            b1 += fmaxf(bf2f((ushort)(hv.x>>16))*scB[1]+shB[1],0.f)+ ct[dB+1];
            b2 += fmaxf(bf2f((ushort)hv.y)*scB[2]+shB[2],0.f)      + ct[dB+2];
            b3 += fmaxf(bf2f((ushort)(hv.y>>16))*scB[3]+shB[3],0.f)+ ct[dB+3];
          }
        } else {
          float4 hv = *(const float4*)(hf + (size_t)src*DD + dA);
          a0 += hv.x + ct[dA+0]; a1 += hv.y + ct[dA+1];
          a2 += hv.z + ct[dA+2]; a3 += hv.w + ct[dA+3];
          if (validB){
            float4 hv2 = *(const float4*)(hf + (size_t)src*DD + dB);
            b0 += hv2.x + ct[dB+0]; b1 += hv2.y + ct[dB+1];
            b2 += hv2.z + ct[dB+2]; b3 += hv2.w + ct[dB+3];
          }
        }
      }
    }
    ushort* ag = agg + (size_t)row*KA1;
    uint2 oA; oA.x = pk2(a0, a1); oA.y = pk2(a2, a3);
    *(uint2*)(ag + dA) = oA;
    if (laneB){
      uint2 oB;
      if (validB){ oB.x = pk2(b0, b1); oB.y = pk2(b2, b3); }
      else       { oB.x = 0; oB.y = 0; }
      *(uint2*)(ag + dB) = oB;
    }
  }
}

// ---- GEMM variant A (for GEMM1, kTiles=10): 128x128 tile, 4 waves,
// ---- 5-buf depth-4 counted vmcnt. Measured ~105us on this shape (r7). ----
template<int OUT_BF16, int RELU, int STATS>
__global__ __launch_bounds__(256) void gemm_128(
    const ushort* __restrict__ A, int lda,
    const ushort* __restrict__ B, int ldb,
    void* __restrict__ Cp, int ldc,
    int kTiles, const float* __restrict__ bias, int biasN,
    int Mvalid, int Nvalid, int nColTiles, float* __restrict__ statf)
{
  __shared__ ushort As[5][4096];
  __shared__ ushort Bs[5][4096];
  int tid = threadIdx.x;
  int lane = tid & 63, w = tid >> 6;
  int wm = (w >> 1) * 64, wn = (w & 1) * 64;

  int nwg = gridDim.x;
  int q = nwg >> 3, r = nwg & 7;
  int xcd = blockIdx.x & 7, idx = blockIdx.x >> 3;
  int bid = (xcd < r ? xcd * (q + 1) : r * (q + 1) + (xcd - r) * q) + idx;
  int m0 = (bid / nColTiles) * 128;
  int n0 = (bid % nColTiles) * 128;

  int r0 = tid >> 2;
  int kc = ((tid & 3) ^ ((tid >> 3) & 3)) * 8;
  const ushort* Ap = A + (size_t)(m0 + r0)*lda + kc;
  const ushort* Bp = B + (size_t)(n0 + r0)*ldb + kc;

  f32x4 acc[4][4] = {};

#define STAGE(buf, kt) do { \
    int _ko = (kt) * 32; \
    __builtin_amdgcn_global_load_lds(GLBP(Ap + _ko),                  LDSP(&As[buf][w*512]),        16, 0, 0); \
    __builtin_amdgcn_global_load_lds(GLBP(Ap + _ko + (size_t)64*lda), LDSP(&As[buf][w*512 + 2048]), 16, 0, 0); \
    __builtin_amdgcn_global_load_lds(GLBP(Bp + _ko),                  LDSP(&Bs[buf][w*512]),        16, 0, 0); \
    __builtin_amdgcn_global_load_lds(GLBP(Bp + _ko + (size_t)64*ldb), LDSP(&Bs[buf][w*512 + 2048]), 16, 0, 0); \
  } while (0)

  STAGE(0, 0); STAGE(1, 1); STAGE(2, 2); STAGE(3, 3);
  WAITV(12);
  __builtin_amdgcn_s_barrier();

  int fr = lane & 15;
  int ko8 = (((lane >> 4) ^ ((fr >> 1) & 3))) * 8;
  int cur = 0;
  for (int kt = 0; kt < kTiles; ++kt){
    int sb = cur + 4; if (sb >= 5) sb -= 5;
    if (kt + 4 < kTiles) STAGE(sb, kt + 4);
    short8 af[4], bfv[4];
    #pragma unroll
    for (int i = 0; i < 4; ++i)
      af[i] = *(const short8*)&As[cur][(wm + i*16 + fr)*32 + ko8];
    #pragma unroll
    for (int j = 0; j < 4; ++j)
      bfv[j] = *(const short8*)&Bs[cur][(wn + j*16 + fr)*32 + ko8];
    #pragma unroll
    for (int i = 0; i < 4; ++i)
      #pragma unroll
      for (int j = 0; j < 4; ++j)
        acc[i][j] = __builtin_amdgcn_mfma_f32_16x16x32_bf16(af[i], bfv[j], acc[i][j], 0, 0, 0);
    if (kt + 1 < kTiles){
      int rem = kTiles - kt;
      if      (rem >= 5) WAITV(12);
      else if (rem == 4) WAITV(8);
      else if (rem == 3) WAITV(4);
      else               WAITV(0);
      __builtin_amdgcn_s_barrier();
    }
    cur = cur + 1; if (cur >= 5) cur = 0;
  }
#undef STAGE

  int cc = lane & 15, cr = (lane >> 4) * 4;
  float ps[4], pq[4];
  if (STATS){
    #pragma unroll
    for (int j = 0; j < 4; ++j){ ps[j] = 0.0f; pq[j] = 0.0f; }
  }
  #pragma unroll
  for (int i = 0; i < 4; ++i){
    #pragma unroll
    for (int j = 0; j < 4; ++j){
      int col = n0 + wn + j*16 + cc;
      if (col >= Nvalid) continue;
      float bv = (col < biasN) ? bias[col] : 0.0f;
      #pragma unroll
      for (int r2 = 0; r2 < 4; ++r2){
        int row = m0 + wm + i*16 + cr + r2;
        if (row < Mvalid){
          float v = acc[i][j][r2] + bv;
          if (RELU) v = fmaxf(v, 0.0f);
          if (OUT_BF16) ((ushort*)Cp)[(size_t)row*ldc + col] = f2bf(v);
          else          ((float*) Cp)[(size_t)row*ldc + col] = v;
          if (STATS){ ps[j] += v; pq[j] += v * v; }
        }
      }
    }
  }
  if (STATS){
    #pragma unroll
    for (int j = 0; j < 4; ++j){
      float s = ps[j], qv = pq[j];
      s += __shfl_xor(s, 16); qv += __shfl_xor(qv, 16);
      s += __shfl_xor(s, 32); qv += __shfl_xor(qv, 32);
      int col = n0 + wn + j*16 + cc;
      if ((lane >> 4) == 0 && col < Nvalid){
        unsafeAtomicAdd(&statf[col], s);
        unsafeAtomicAdd(&statf[N2T + col], qv);
      }
    }
  }
}

// ---- GEMM variant B (for GEMM2, kTiles=19): 256x128 tile, 8 waves,
// ---- 3-buf depth-2 counted vmcnt. Measured ~65us on this shape (r6). -----
template<int OUT_BF16, int RELU, int STATS>
__global__ __launch_bounds__(512) void gemm_256(
    const ushort* __restrict__ A, int lda,
    const ushort* __restrict__ B, int ldb,
    void* __restrict__ Cp, int ldc,
    int kTiles, const float* __restrict__ bias, int biasN,
    int Mvalid, int Nvalid, int nColTiles, float* __restrict__ statf)
{
  __shared__ ushort As[3][8192];    // 256 rows x 32
  __shared__ ushort Bs[3][4096];    // 128 rows x 32
  int tid = threadIdx.x;
  int lane = tid & 63, w = tid >> 6;          // w: 0..7
  int wm = (w >> 1) * 64, wn = (w & 1) * 64;  // wm: 0..192, wn: 0/64

  int nwg = gridDim.x;
  int q = nwg >> 3, r = nwg & 7;
  int xcd = blockIdx.x & 7, idx = blockIdx.x >> 3;
  int bid = (xcd < r ? xcd * (q + 1) : r * (q + 1) + (xcd - r) * q) + idx;
  int m0 = (bid / nColTiles) * 256;
  int n0 = (bid % nColTiles) * 128;

  int r0 = tid >> 2;                            // 0..127
  int kc = ((tid & 3) ^ ((tid >> 3) & 3)) * 8;
  const ushort* Ap = A + (size_t)(m0 + r0)*lda + kc;
  const ushort* Bp = B + (size_t)(n0 + r0)*ldb + kc;

  f32x4 acc[4][4] = {};

#define STAGE(buf, kt) do { \
    int _ko = (kt) * 32; \
    __builtin_amdgcn_global_load_lds(GLBP(Ap + _ko),                   LDSP(&As[buf][w*512]),        16, 0, 0); \
    __builtin_amdgcn_global_load_lds(GLBP(Ap + _ko + (size_t)128*lda), LDSP(&As[buf][w*512 + 4096]), 16, 0, 0); \
    __builtin_amdgcn_global_load_lds(GLBP(Bp + _ko),                   LDSP(&Bs[buf][w*512]),        16, 0, 0); \
  } while (0)

  STAGE(0, 0);
  STAGE(1, 1);
  WAITV(3);
  __builtin_amdgcn_s_barrier();

  int fr = lane & 15;
  int ko8 = (((lane >> 4) ^ ((fr >> 1) & 3))) * 8;
  int cur = 0;
  for (int kt = 0; kt < kTiles; ++kt){
    int sb = cur + 2; if (sb >= 3) sb -= 3;
    if (kt + 2 < kTiles) STAGE(sb, kt + 2);
    short8 af[4], bfv[4];
    #pragma unroll
    for (int i = 0; i < 4; ++i)
      af[i] = *(const short8*)&As[cur][(wm + i*16 + fr)*32 + ko8];
    #pragma unroll
    for (int j = 0; j < 4; ++j)
      bfv[j] = *(const short8*)&Bs[cur][(wn + j*16 + fr)*32 + ko8];
    #pragma unroll
    for (int i = 0; i < 4; ++i)
      #pragma unroll
      for (int j = 0; j < 4; ++j)
        acc[i][j] = __builtin_amdgcn_mfma_f32_16x16x32_bf16(af[i], bfv[j], acc[i][j], 0, 0, 0);
    if (kt + 1 < kTiles){
      if (kt + 2 < kTiles) WAITV(3);
      else                 WAITV(0);
      __builtin_amdgcn_s_barrier();
    }
    cur = cur + 1; if (cur >= 3) cur = 0;
  }
#undef STAGE

  int cc = lane & 15, cr = (lane >> 4) * 4;
  float ps[4], pq[4];
  if (STATS){
    #pragma unroll
    for (int j = 0; j < 4; ++j){ ps[j] = 0.0f; pq[j] = 0.0f; }
  }
  #pragma unroll
  for (int i = 0; i < 4; ++i){
    #pragma unroll
    for (int j = 0; j < 4; ++j){
      int col = n0 + wn + j*16 + cc;
      if (col >= Nvalid) continue;
      float bv = (col < biasN) ? bias[col] : 0.0f;
      #pragma unroll
      for (int r2 = 0; r2 < 4; ++r2){
        int row = m0 + wm + i*16 + cr + r2;
        if (row < Mvalid){
          float v = acc[i][j][r2] + bv;
          if (RELU) v = fmaxf(v, 0.0f);
          if (OUT_BF16) ((ushort*)Cp)[(size_t)row*ldc + col] = f2bf(v);
          else          ((float*) Cp)[(size_t)row*ldc + col] = v;
          if (STATS){ ps[j] += v; pq[j] += v * v; }
        }
      }
    }
  }
  if (STATS){
    #pragma unroll
    for (int j = 0; j < 4; ++j){
      float s = ps[j], qv = pq[j];
      s += __shfl_xor(s, 16); qv += __shfl_xor(qv, 16);
      s += __shfl_xor(s, 32); qv += __shfl_xor(qv, 32);
      int col = n0 + wn + j*16 + cc;
      if ((lane >> 4) == 0 && col < Nvalid){
        unsafeAtomicAdd(&statf[col], s);
        unsafeAtomicAdd(&statf[N2T + col], qv);
      }
    }
  }
}

// ---------------- per-column scale/shift from stats ------------------------
__global__ void make_norm(const float* __restrict__ statf, const float* __restrict__ gamma,
                          const float* __restrict__ beta, float2* __restrict__ ss){
  int d = threadIdx.x;
  if (d >= DD) return;
  double mu = (double)statf[d] / (double)NN;
  double var = (double)statf[N2T + d] / (double)NN - mu * mu;
  float inv = rsqrtf((float)var + 1e-5f);
  float sc = inv * gamma[d];
  ss[d] = make_float2(sc, beta[d] - (float)mu * sc);
}

// ---------------- final norm (no relu) -> d_out ----------------------------
__global__ void apply_norm(const float* __restrict__ m2, const float2* __restrict__ ss,
                           float* __restrict__ out){
  int row = blockIdx.x;
  int d = threadIdx.x;
  if (d >= DD) return;
  float2 s = ss[d];
  out[(size_t)row*DD + d] = m2[(size_t)row*DD + d] * s.x + s.y;
}

extern "C" void kernel_launch(void* const* d_in, const int* in_sizes, int n_in,
                              void* d_out, int out_size, void* d_ws, size_t ws_size,
                              hipStream_t stream) {
  const float* x     = (const float*)d_in[0];
  const int*   ei    = (const int*)  d_in[1];
  const int*   ea    = (const int*)  d_in[2];
  const float* W1    = (const float*)d_in[3];
  const float* b1    = (const float*)d_in[4];
  const float* W2    = (const float*)d_in[5];
  const float* b2    = (const float*)d_in[6];
  const float* E1    = (const float*)d_in[7];
  const float* E2    = (const float*)d_in[8];
  const float* gamma = (const float*)d_in[9];
  const float* beta  = (const float*)d_in[10];

  char* p = (char*)d_ws;
  float*  m2buf = (float*) p; p += (size_t)NN * DD * 4;          // 120,000,000
  ushort* m2bf  = (ushort*)p; p += (size_t)NN * DDB * 2;         //  60,800,000
  ushort* agg   = (ushort*)p; p += (size_t)MPAD * KA1 * 2;       //  64,061,440
  ushort* m1    = (ushort*)p; p += (size_t)MPAD * N1 * 2;        // 121,716,736
  ushort* W1T   = (ushort*)p; p += (size_t)NL * N1T * KA1 * 2;   //   2,048,000
  ushort* W2T   = (ushort*)p; p += (size_t)NL * N2T * K2 * 2;    //   2,334,720
  float*  ctab  = (float*) p; p += (size_t)NL * NCMB * DDB * 4;  //     115,520
  int*    deg   = (int*)   p; p += (size_t)NN * 4;               //     400,000
  int*    rs    = (int*)   p; p += (size_t)(NN + 16) * 4;        //     400,064
  int*    bsum  = (int*)   p; p += (size_t)512 * 4;              //       2,048
  int*    cursor= (int*)   p; p += (size_t)NN * 4;               //     400,000
  int*    edges = (int*)   p; p += (size_t)NE * 4;               //   1,000,000
  float*  statf = (float*) p; p += (size_t)2 * N2T * 4;          //       3,072
  float2* ss    = (float2*)p;                                    //       2,400

  // once-per-launch prep
  {
    int total = NL*N1T*KA1 + NL*N2T*K2;
    prep_weights<<<(total + 255)/256, 256, 0, stream>>>(W1, W2, W1T, W2T);
    int tc = NL * NCMB * DDB;
    prep_ctab<<<(tc + 255)/256, 256, 0, stream>>>(E1, E2, ctab);
  }
  hipMemsetAsync(deg, 0, (size_t)NN*4, stream);
  hipMemsetAsync(cursor, 0, (size_t)NN*4, stream);
  csr_count<<<(NE + 255)/256, 256, 0, stream>>>(ei, deg);
  scan_blk<<<NBLK, 256, 0, stream>>>(deg, rs, bsum);
  scan_top<<<1, 512, 0, stream>>>(bsum);
  scan_add<<<NBLK, 256, 0, stream>>>(rs, bsum);
  csr_fill<<<(NE + 255)/256, 256, 0, stream>>>(ei, ea, rs, cursor, edges);

  for (int l = 0; l < NL; ++l){
    const float* ctab_l = ctab + (size_t)l * NCMB * DDB;

    if (l == 0)
      gather_agg<0><<<2048, 256, 0, stream>>>(x, nullptr, ctab_l, rs, edges, agg);
    else
      gather_agg<1><<<2048, 256, 0, stream>>>(m2bf, ss, ctab_l, rs, edges, agg);

    // m1 = relu(agg @ W1 + b1)  -> bf16 [MPAD][608]  (128-tile, depth-4)
    gemm_128<1,1,0><<<(MPAD/128) * (N1T/128), 256, 0, stream>>>(
        agg, KA1, W1T + (size_t)l*N1T*KA1, KA1, m1, N1, KA1/32,
        b1 + (size_t)l*2*DD, 2*DD, MPAD, N1, N1T/128, nullptr);

    hipMemsetAsync(statf, 0, (size_t)2*N2T*4, stream);

    // m2 = m1 @ W2 + b2 (+ fused stats)  (256-tile, depth-2)
    if (l < NL - 1)
      gemm_256<1,0,1><<<(MPAD/256) * (N2T/128), 512, 0, stream>>>(
          m1, N1, W2T + (size_t)l*N2T*K2, K2, m2bf, DDB, K2/32,
          b2 + (size_t)l*DD, DD, NN, DD, N2T/128, statf);
    else
      gemm_256<0,0,1><<<(MPAD/256) * (N2T/128), 512, 0, stream>>>(
          m1, N1, W2T + (size_t)l*N2T*K2, K2, m2buf, DD, K2/32,
          b2 + (size_t)l*DD, DD, NN, DD, N2T/128, statf);

    make_norm<<<1, 320, 0, stream>>>(statf, gamma + (size_t)l*DD, beta + (size_t)l*DD, ss);
  }
  apply_norm<<<NN, 320, 0, stream>>>(m2buf, ss, (float*)d_out);
}

// Round 10
// 1706.140 us; speedup vs baseline: 1.1065x; 1.0275x over previous
//
#include <hip/hip_runtime.h>
#include <hip/hip_bf16.h>

#define NN 100000
#define NE 250000
#define DD 300
#define DDB 304       // bf16 h row stride (16B aligned)
#define NL 5
#define MPAD 100096   // 782*128
#define KA1 320       // padded K for GEMM1 (300->320)
#define N1T 640       // padded rows of W1T (5 blocks * 128)
#define N2T 384       // padded rows of W2T (300->384)
#define K2P 640       // padded k-stride of W2T (600->640, zero-filled)
#define NBLK 391      // ceil(NN/256)
#define NCMB 19       // 18 (bt*3+bd) combos + self at 18

typedef __attribute__((ext_vector_type(8))) short short8;
typedef __attribute__((ext_vector_type(4))) float f32x4;

#define GLBP(x) ((const __attribute__((address_space(1))) unsigned int*)(x))
#define LDSP(x) ((__attribute__((address_space(3))) unsigned int*)(x))
#define WAITV(N) asm volatile("s_waitcnt vmcnt(" #N ")" ::: "memory")

__device__ __forceinline__ ushort f2bf(float f){
  unsigned u = __float_as_uint(f);
  u += 0x7FFFu + ((u >> 16) & 1u);
  return (ushort)(u >> 16);
}
__device__ __forceinline__ float bf2f(ushort h){
  return __uint_as_float((unsigned)h << 16);
}
__device__ __forceinline__ unsigned pk2(float a, float b){
  return (unsigned)f2bf(a) | ((unsigned)f2bf(b) << 16);
}

// ---------------- weight prep: transpose + f32->bf16, zero-padded ----------
__global__ void prep_weights(const float* __restrict__ W1, const float* __restrict__ W2,
                             ushort* __restrict__ W1T, ushort* __restrict__ W2T){
  int idx = blockIdx.x * 256 + threadIdx.x;
  const int total1 = NL * N1T * KA1;
  const int total2 = NL * N2T * K2P;
  if (idx < total1){
    int l = idx / (N1T * KA1);
    int rem = idx % (N1T * KA1);
    int n = rem / KA1, k = rem % KA1;
    float v = (n < 2*DD && k < DD) ? W1[(size_t)l*DD*2*DD + (size_t)k*2*DD + n] : 0.0f;
    W1T[idx] = f2bf(v);
  } else {
    int idx2 = idx - total1;
    if (idx2 < total2){
      int l = idx2 / (N2T * K2P);
      int rem = idx2 % (N2T * K2P);
      int n = rem / K2P, k = rem % K2P;
      float v = (n < DD && k < 2*DD) ? W2[(size_t)l*2*DD*DD + (size_t)k*DD + n] : 0.0f;
      W2T[idx2] = f2bf(v);
    }
  }
}

// -------- combo tables: ctab[l][c][d] = E1[l][c/3][d] + E2[l][c%3][d] ------
__global__ void prep_ctab(const float* __restrict__ E1, const float* __restrict__ E2,
                          float* __restrict__ ctab){
  int idx = blockIdx.x * 256 + threadIdx.x;
  if (idx >= NL * NCMB * DDB) return;
  int l = idx / (NCMB * DDB);
  int rem = idx % (NCMB * DDB);
  int c = rem / DDB, d = rem % DDB;
  float v = 0.0f;
  if (d < DD){
    int bt = (c < 18) ? (c / 3) : 4;
    int bd = (c < 18) ? (c % 3) : 0;
    v = E1[(size_t)l*6*DD + bt*DD + d] + E2[(size_t)l*3*DD + bd*DD + d];
  }
  ctab[idx] = v;
}

// ---------------- CSR build ------------------------------------------------
__global__ void csr_count(const int* __restrict__ ei, int* __restrict__ deg){
  int e = blockIdx.x * 256 + threadIdx.x;
  if (e < NE) atomicAdd(&deg[ei[NE + e]], 1);
}

__global__ void scan_blk(const int* __restrict__ deg, int* __restrict__ rs, int* __restrict__ bsum){
  __shared__ int tmp[256];
  int i = blockIdx.x * 256 + threadIdx.x;
  int v = (i < NN) ? deg[i] : 0;
  tmp[threadIdx.x] = v;
  __syncthreads();
  #pragma unroll
  for (int off = 1; off < 256; off <<= 1){
    int t = (threadIdx.x >= off) ? tmp[threadIdx.x - off] : 0;
    __syncthreads();
    tmp[threadIdx.x] += t;
    __syncthreads();
  }
  if (i < NN) rs[i] = tmp[threadIdx.x] - v;   // exclusive
  if (threadIdx.x == 255) bsum[blockIdx.x] = tmp[255];
}

__global__ void scan_top(int* __restrict__ bsum){
  __shared__ int tmp[512];
  int v = (threadIdx.x < NBLK) ? bsum[threadIdx.x] : 0;
  tmp[threadIdx.x] = v;
  __syncthreads();
  #pragma unroll
  for (int off = 1; off < 512; off <<= 1){
    int t = (threadIdx.x >= off) ? tmp[threadIdx.x - off] : 0;
    __syncthreads();
    tmp[threadIdx.x] += t;
    __syncthreads();
  }
  if (threadIdx.x < NBLK) bsum[threadIdx.x] = tmp[threadIdx.x] - v; // exclusive
}

__global__ void scan_add(int* __restrict__ rs, const int* __restrict__ bsum){
  int i = blockIdx.x * 256 + threadIdx.x;
  if (i < NN) rs[i] += bsum[blockIdx.x];
  if (i == 0) rs[NN] = NE;
}

__global__ void csr_fill(const int* __restrict__ ei, const int* __restrict__ ea,
                         const int* __restrict__ rs, int* __restrict__ cursor,
                         int* __restrict__ edges){
  int e = blockIdx.x * 256 + threadIdx.x;
  if (e < NE){
    int dst = ei[NE + e];
    int src = ei[e];
    int c = ea[2*e] * 3 + ea[2*e + 1];
    int p = rs[dst] + atomicAdd(&cursor[dst], 1);
    edges[p] = src | (c << 20);
  }
}

// ---- gather: wave-per-row, grid-stride. 2 tranches: dA=lane*4 (0..255),
// ---- dB=256+lane*4 (lanes 0..15; data valid lanes 0..10). ----
template<int HBF>
__global__ __launch_bounds__(256) void gather_agg(
    const void* __restrict__ hp, const float2* __restrict__ ss,
    const float* __restrict__ ctab_l,
    const int* __restrict__ rs, const int* __restrict__ edges,
    ushort* __restrict__ agg)
{
  int lane = threadIdx.x & 63;
  int wq = __builtin_amdgcn_readfirstlane(threadIdx.x >> 6);
  int wid = blockIdx.x * 4 + wq;
  int nw = gridDim.x * 4;
  int dA = lane * 4;
  int dB = 256 + lane * 4;
  bool laneB  = (lane < 16);
  bool validB = (dB < DD);         // lanes 0..10

  float scA[4], shA[4], scB[4], shB[4];
  if (HBF){
    #pragma unroll
    for (int j = 0; j < 4; ++j){
      float2 s = ss[dA + j]; scA[j] = s.x; shA[j] = s.y;
    }
    if (validB){
      #pragma unroll
      for (int j = 0; j < 4; ++j){
        float2 s = ss[dB + j]; scB[j] = s.x; shB[j] = s.y;
      }
    }
  }

  const float*  hf = (const float*)hp;
  const ushort* hb = (const ushort*)hp;
  const float* ctS = ctab_l + 18*DDB;

  for (int row = wid; row < MPAD; row += nw){
    float a0=0,a1=0,a2=0,a3=0, b0=0,b1v=0,b2v=0,b3=0;
    if (row < NN){
      if (HBF){
        uint2 hw = *(const uint2*)(hb + (size_t)row*DDB + dA);
        a0 = fmaxf(bf2f((ushort)hw.x)*scA[0]+shA[0],0.f)      + ctS[dA+0];
        a1 = fmaxf(bf2f((ushort)(hw.x>>16))*scA[1]+shA[1],0.f)+ ctS[dA+1];
        a2 = fmaxf(bf2f((ushort)hw.y)*scA[2]+shA[2],0.f)      + ctS[dA+2];
        a3 = fmaxf(bf2f((ushort)(hw.y>>16))*scA[3]+shA[3],0.f)+ ctS[dA+3];
        if (validB){
          uint2 hv = *(const uint2*)(hb + (size_t)row*DDB + dB);
          b0  = fmaxf(bf2f((ushort)hv.x)*scB[0]+shB[0],0.f)      + ctS[dB+0];
          b1v = fmaxf(bf2f((ushort)(hv.x>>16))*scB[1]+shB[1],0.f)+ ctS[dB+1];
          b2v = fmaxf(bf2f((ushort)hv.y)*scB[2]+shB[2],0.f)      + ctS[dB+2];
          b3  = fmaxf(bf2f((ushort)(hv.y>>16))*scB[3]+shB[3],0.f)+ ctS[dB+3];
        }
      } else {
        float4 hv = *(const float4*)(hf + (size_t)row*DD + dA);
        a0 = hv.x + ctS[dA+0]; a1 = hv.y + ctS[dA+1];
        a2 = hv.z + ctS[dA+2]; a3 = hv.w + ctS[dA+3];
        if (validB){
          float4 hv2 = *(const float4*)(hf + (size_t)row*DD + dB);
          b0 = hv2.x + ctS[dB+0]; b1v = hv2.y + ctS[dB+1];
          b2v = hv2.z + ctS[dB+2]; b3 = hv2.w + ctS[dB+3];
        }
      }
      int p = rs[row], pe = rs[row + 1];
      for (; p < pe; ++p){
        int ew = edges[p];
        int src = ew & 0xFFFFF;
        const float* ct = ctab_l + (ew >> 20)*DDB;
        if (HBF){
          uint2 hw = *(const uint2*)(hb + (size_t)src*DDB + dA);
          a0 += fmaxf(bf2f((ushort)hw.x)*scA[0]+shA[0],0.f)      + ct[dA+0];
          a1 += fmaxf(bf2f((ushort)(hw.x>>16))*scA[1]+shA[1],0.f)+ ct[dA+1];
          a2 += fmaxf(bf2f((ushort)hw.y)*scA[2]+shA[2],0.f)      + ct[dA+2];
          a3 += fmaxf(bf2f((ushort)(hw.y>>16))*scA[3]+shA[3],0.f)+ ct[dA+3];
          if (validB){
            uint2 hv = *(const uint2*)(hb + (size_t)src*DDB + dB);
            b0  += fmaxf(bf2f((ushort)hv.x)*scB[0]+shB[0],0.f)      + ct[dB+0];
            b1v += fmaxf(bf2f((ushort)(hv.x>>16))*scB[1]+shB[1],0.f)+ ct[dB+1];
            b2v += fmaxf(bf2f((ushort)hv.y)*scB[2]+shB[2],0.f)      + ct[dB+2];
            b3  += fmaxf(bf2f((ushort)(hv.y>>16))*scB[3]+shB[3],0.f)+ ct[dB+3];
          }
        } else {
          float4 hv = *(const float4*)(hf + (size_t)src*DD + dA);
          a0 += hv.x + ct[dA+0]; a1 += hv.y + ct[dA+1];
          a2 += hv.z + ct[dA+2]; a3 += hv.w + ct[dA+3];
          if (validB){
            float4 hv2 = *(const float4*)(hf + (size_t)src*DD + dB);
            b0 += hv2.x + ct[dB+0]; b1v += hv2.y + ct[dB+1];
            b2v += hv2.z + ct[dB+2]; b3 += hv2.w + ct[dB+3];
          }
        }
      }
    }
    ushort* ag = agg + (size_t)row*KA1;
    uint2 oA; oA.x = pk2(a0, a1); oA.y = pk2(a2, a3);
    *(uint2*)(ag + dA) = oA;
    if (laneB){
      uint2 oB;
      if (validB){ oB.x = pk2(b0, b1v); oB.y = pk2(b2v, b3); }
      else       { oB.x = 0; oB.y = 0; }
      *(uint2*)(ag + dB) = oB;
    }
  }
}

// ==== FUSED MLP: m2 = (relu(agg@W1+b1)) @ W2 + b2, m1 never leaves LDS. ====
// Block = 128 rows, 512 thr (8 waves). Per jb (5 blocks of 128 m1-cols):
//   phase A: P = relu(agg_tile @ W1T[jb] + b1) -> LDS [128][128] bf16
//   phase B: acc2 += P @ W2T[:, jb*128..+128]  (4 sub-K of 32)
// W2T tile [384][32]: each gload_lds = 16 rows (512 ushorts); wave w's three
// loads land at rows {w*16, 128+w*16, 256+w*16} = ushort offs {w*512,
// w*512+4096, w*512+8192}.  (r9 bug: +2048/+4096 collided across waves.)
template<int OUT_BF16>
__global__ __launch_bounds__(512) void mlp_fused(
    const ushort* __restrict__ agg,      // [MPAD][KA1]
    const ushort* __restrict__ W1T_l,    // [N1T][KA1]
    const ushort* __restrict__ W2T_l,    // [N2T][K2P]
    const float* __restrict__ b1_l,      // [600]
    const float* __restrict__ b2_l,      // [300]
    void* __restrict__ Cp, int ldc,
    float* __restrict__ statf)
{
  __shared__ ushort Sa[3][4096];    // agg tiles  [128][32]
  __shared__ ushort Sb[3][4096];    // W1T tiles  [128][32]
  __shared__ ushort Ws[3][12288];   // W2T tiles  [384][32]
  __shared__ ushort Pt[16384];      // P [128][128], granule-swizzled

  int tid = threadIdx.x;
  int lane = tid & 63, w = tid >> 6;
  int wmA = (w >> 2) * 64;          // rows for both phases
  int wnA = (w & 3) * 32;           // phase A col block
  int wnB = (w & 3) * 96;           // phase B col block

  int nwg = gridDim.x;
  int q = nwg >> 3, r = nwg & 7;
  int xcd = blockIdx.x & 7, bix = blockIdx.x >> 3;
  int bid = (xcd < r ? xcd*(q+1) : r*(q+1) + (xcd-r)*q) + bix;
  int m0 = bid * 128;

  int r0 = tid >> 2;                            // 0..127
  int kc = ((tid & 3) ^ ((tid >> 3) & 3)) * 8;  // inverse-swizzled src granule
  const ushort* Ap = agg + (size_t)(m0 + r0)*KA1 + kc;

  int fr = lane & 15;
  int kq = lane >> 4;
  int ko8 = (kq ^ ((fr >> 1) & 3)) * 8;         // swizzled read offset
  int cc = lane & 15, cr = kq * 4;

  f32x4 acc2[4][6] = {};            // C2 accumulator, lives across jb

#define STAGE_A(buf, kt) do { \
    int _ko = (kt) * 32; \
    __builtin_amdgcn_global_load_lds(GLBP(Ap + _ko),  LDSP(&Sa[buf][w*512]), 16, 0, 0); \
    __builtin_amdgcn_global_load_lds(GLBP(W1p + _ko), LDSP(&Sb[buf][w*512]), 16, 0, 0); \
  } while (0)
#define STAGE_W(buf, s) do { \
    int _ko = (s) * 32; \
    __builtin_amdgcn_global_load_lds(GLBP(W2p + _ko),                   LDSP(&Ws[buf][w*512]),        16, 0, 0); \
    __builtin_amdgcn_global_load_lds(GLBP(W2p + _ko + (size_t)128*K2P), LDSP(&Ws[buf][w*512 + 4096]), 16, 0, 0); \
    __builtin_amdgcn_global_load_lds(GLBP(W2p + _ko + (size_t)256*K2P), LDSP(&Ws[buf][w*512 + 8192]), 16, 0, 0); \
  } while (0)

  #pragma unroll 1
  for (int jb = 0; jb < 5; ++jb){
    const ushort* W1p = W1T_l + (size_t)(jb*128 + r0)*KA1 + kc;
    const ushort* W2p = W2T_l + (size_t)r0*K2P + jb*128 + kc;

    // ---------------- phase A: P = relu(agg @ W1T[jb] + b1) ----------------
    f32x4 accA[4][2] = {};
    STAGE_A(0, 0); STAGE_A(1, 1);
    WAITV(2);                       // own tile-0 loads landed
    __builtin_amdgcn_s_barrier();   // all waves' tile-0 landed
    int cur = 0;
    for (int kt = 0; kt < 10; ++kt){
      int sb = cur + 2; if (sb >= 3) sb -= 3;
      if (kt + 2 < 10) STAGE_A(sb, kt + 2);
      short8 af[4], bw[2];
      #pragma unroll
      for (int i = 0; i < 4; ++i)
        af[i] = *(const short8*)&Sa[cur][(wmA + i*16 + fr)*32 + ko8];
      #pragma unroll
      for (int j2 = 0; j2 < 2; ++j2)
        bw[j2] = *(const short8*)&Sb[cur][(wnA + j2*16 + fr)*32 + ko8];
      #pragma unroll
      for (int i = 0; i < 4; ++i)
        #pragma unroll
        for (int j2 = 0; j2 < 2; ++j2)
          accA[i][j2] = __builtin_amdgcn_mfma_f32_16x16x32_bf16(af[i], bw[j2], accA[i][j2], 0, 0, 0);
      if (kt + 1 < 10){
        if (kt + 2 < 10) WAITV(2);  // tile kt+1 landed; kt+2 in flight
        else             WAITV(0);
        __builtin_amdgcn_s_barrier();
      }
      cur = cur + 1; if (cur >= 3) cur = 0;
    }
    // write P (swizzled): phys granule = (col>>3) ^ ((row>>1)&7)
    #pragma unroll
    for (int i = 0; i < 4; ++i){
      #pragma unroll
      for (int j2 = 0; j2 < 2; ++j2){
        int pcol = wnA + j2*16 + cc;
        int gcol = jb*128 + pcol;
        float bv = (gcol < 2*DD) ? b1_l[gcol] : 0.0f;
        #pragma unroll
        for (int r2 = 0; r2 < 4; ++r2){
          int prow = wmA + i*16 + cr + r2;
          float v = fmaxf(accA[i][j2][r2] + bv, 0.0f);
          int gp = (pcol >> 3) ^ ((prow >> 1) & 7);
          Pt[prow*128 + gp*8 + (pcol & 7)] = f2bf(v);
        }
      }
    }
    // issue W2 prologue stages, then make P visible to all waves
    STAGE_W(0, 0); STAGE_W(1, 1);           // vmcnt: 6 outstanding
    asm volatile("s_waitcnt lgkmcnt(0)" ::: "memory");   // own P writes done
    __builtin_amdgcn_sched_barrier(0);
    __builtin_amdgcn_s_barrier();           // all waves' P visible
    WAITV(3);                               // own s0 loads landed (s1 in flight)
    __builtin_amdgcn_s_barrier();

    // ---------------- phase B: acc2 += P @ W2T[:, jb-block] ----------------
    #pragma unroll
    for (int s = 0; s < 4; ++s){
      if (s + 2 < 4) STAGE_W((s + 2) % 3, s + 2);
      if      (s == 1) WAITV(6);   // s1 landed (s2,s3 in flight)
      else if (s == 2) WAITV(3);   // s2 landed
      else if (s == 3) WAITV(0);   // s3 landed
      if (s) __builtin_amdgcn_s_barrier();
      short8 pf[4], wf[6];
      #pragma unroll
      for (int i = 0; i < 4; ++i){
        int prow = wmA + i*16 + fr;
        int gp = (s*4 + kq) ^ ((prow >> 1) & 7);
        pf[i] = *(const short8*)&Pt[prow*128 + gp*8];
      }
      #pragma unroll
      for (int j2 = 0; j2 < 6; ++j2)
        wf[j2] = *(const short8*)&Ws[s % 3][(wnB + j2*16 + fr)*32 + ko8];
      #pragma unroll
      for (int i = 0; i < 4; ++i)
        #pragma unroll
        for (int j2 = 0; j2 < 6; ++j2)
          acc2[i][j2] = __builtin_amdgcn_mfma_f32_16x16x32_bf16(pf[i], wf[j2], acc2[i][j2], 0, 0, 0);
      __builtin_amdgcn_s_barrier();
    }
  }
#undef STAGE_A
#undef STAGE_W

  // ---------------- epilogue: bias + store + fused BN stats ----------------
  float ps[6], pq[6];
  #pragma unroll
  for (int j2 = 0; j2 < 6; ++j2){ ps[j2] = 0.0f; pq[j2] = 0.0f; }
  #pragma unroll
  for (int i = 0; i < 4; ++i){
    #pragma unroll
    for (int j2 = 0; j2 < 6; ++j2){
      int col = wnB + j2*16 + cc;
      if (col >= DD) continue;
      float bv = b2_l[col];
      #pragma unroll
      for (int r2 = 0; r2 < 4; ++r2){
        int row = m0 + wmA + i*16 + cr + r2;
        if (row < NN){
          float v = acc2[i][j2][r2] + bv;
          if (OUT_BF16) ((ushort*)Cp)[(size_t)row*ldc + col] = f2bf(v);
          else          ((float*) Cp)[(size_t)row*ldc + col] = v;
          ps[j2] += v; pq[j2] += v * v;
        }
      }
    }
  }
  #pragma unroll
  for (int j2 = 0; j2 < 6; ++j2){
    float s = ps[j2], qv = pq[j2];
    s += __shfl_xor(s, 16); qv += __shfl_xor(qv, 16);
    s += __shfl_xor(s, 32); qv += __shfl_xor(qv, 32);
    int col = wnB + j2*16 + cc;
    if (kq == 0 && col < DD){
      unsafeAtomicAdd(&statf[col], s);
      unsafeAtomicAdd(&statf[N2T + col], qv);
    }
  }
}

// ---------------- per-column scale/shift from stats ------------------------
__global__ void make_norm(const float* __restrict__ statf, const float* __restrict__ gamma,
                          const float* __restrict__ beta, float2* __restrict__ ss){
  int d = threadIdx.x;
  if (d >= DD) return;
  double mu = (double)statf[d] / (double)NN;
  double var = (double)statf[N2T + d] / (double)NN - mu * mu;
  float inv = rsqrtf((float)var + 1e-5f);
  float sc = inv * gamma[d];
  ss[d] = make_float2(sc, beta[d] - (float)mu * sc);
}

// ---------------- final norm (no relu) -> d_out ----------------------------
__global__ void apply_norm(const float* __restrict__ m2, const float2* __restrict__ ss,
                           float* __restrict__ out){
  int row = blockIdx.x;
  int d = threadIdx.x;
  if (d >= DD) return;
  float2 s = ss[d];
  out[(size_t)row*DD + d] = m2[(size_t)row*DD + d] * s.x + s.y;
}

extern "C" void kernel_launch(void* const* d_in, const int* in_sizes, int n_in,
                              void* d_out, int out_size, void* d_ws, size_t ws_size,
                              hipStream_t stream) {
  const float* x     = (const float*)d_in[0];
  const int*   ei    = (const int*)  d_in[1];
  const int*   ea    = (const int*)  d_in[2];
  const float* W1    = (const float*)d_in[3];
  const float* b1    = (const float*)d_in[4];
  const float* W2    = (const float*)d_in[5];
  const float* b2    = (const float*)d_in[6];
  const float* E1    = (const float*)d_in[7];
  const float* E2    = (const float*)d_in[8];
  const float* gamma = (const float*)d_in[9];
  const float* beta  = (const float*)d_in[10];

  char* p = (char*)d_ws;
  float*  m2buf = (float*) p; p += (size_t)NN * DD * 4;          // 120,000,000
  ushort* m2bf  = (ushort*)p; p += (size_t)NN * DDB * 2;         //  60,800,000
  ushort* agg   = (ushort*)p; p += (size_t)MPAD * KA1 * 2;       //  64,061,440
  ushort* W1T   = (ushort*)p; p += (size_t)NL * N1T * KA1 * 2;   //   2,048,000
  ushort* W2T   = (ushort*)p; p += (size_t)NL * N2T * K2P * 2;   //   2,457,600
  float*  ctab  = (float*) p; p += (size_t)NL * NCMB * DDB * 4;  //     115,520
  int*    deg   = (int*)   p; p += (size_t)NN * 4;               //     400,000
  int*    rs    = (int*)   p; p += (size_t)(NN + 16) * 4;        //     400,064
  int*    bsum  = (int*)   p; p += (size_t)512 * 4;              //       2,048
  int*    cursor= (int*)   p; p += (size_t)NN * 4;               //     400,000
  int*    edges = (int*)   p; p += (size_t)NE * 4;               //   1,000,000
  float*  statf = (float*) p; p += (size_t)2 * N2T * 4;          //       3,072
  float2* ss    = (float2*)p;                                    //       2,400

  // once-per-launch prep
  {
    int total = NL*N1T*KA1 + NL*N2T*K2P;
    prep_weights<<<(total + 255)/256, 256, 0, stream>>>(W1, W2, W1T, W2T);
    int tc = NL * NCMB * DDB;
    prep_ctab<<<(tc + 255)/256, 256, 0, stream>>>(E1, E2, ctab);
  }
  hipMemsetAsync(deg, 0, (size_t)NN*4, stream);
  hipMemsetAsync(cursor, 0, (size_t)NN*4, stream);
  csr_count<<<(NE + 255)/256, 256, 0, stream>>>(ei, deg);
  scan_blk<<<NBLK, 256, 0, stream>>>(deg, rs, bsum);
  scan_top<<<1, 512, 0, stream>>>(bsum);
  scan_add<<<NBLK, 256, 0, stream>>>(rs, bsum);
  csr_fill<<<(NE + 255)/256, 256, 0, stream>>>(ei, ea, rs, cursor, edges);

  for (int l = 0; l < NL; ++l){
    const float* ctab_l = ctab + (size_t)l * NCMB * DDB;

    if (l == 0)
      gather_agg<0><<<2048, 256, 0, stream>>>(x, nullptr, ctab_l, rs, edges, agg);
    else
      gather_agg<1><<<2048, 256, 0, stream>>>(m2bf, ss, ctab_l, rs, edges, agg);

    hipMemsetAsync(statf, 0, (size_t)2*N2T*4, stream);

    if (l < NL - 1)
      mlp_fused<1><<<MPAD/128, 512, 0, stream>>>(
          agg, W1T + (size_t)l*N1T*KA1, W2T + (size_t)l*N2T*K2P,
          b1 + (size_t)l*2*DD, b2 + (size_t)l*DD, m2bf, DDB, statf);
    else
      mlp_fused<0><<<MPAD/128, 512, 0, stream>>>(
          agg, W1T + (size_t)l*N1T*KA1, W2T + (size_t)l*N2T*K2P,
          b1 + (size_t)l*2*DD, b2 + (size_t)l*DD, m2buf, DD, statf);

    make_norm<<<1, 320, 0, stream>>>(statf, gamma + (size_t)l*DD, beta + (size_t)l*DD, ss);
  }
  apply_norm<<<NN, 320, 0, stream>>>(m2buf, ss, (float*)d_out);
}